// Round 6
// baseline (154.824 us; speedup 1.0000x reference)
//
#include <hip/hip_runtime.h>
#include <math.h>

#define B_ 4
#define N_ 2048
#define C_ 64
#define K_ 32
#define BN_ (B_ * N_)  // 8192

// ws float layout (all regions rewritten every launch before being read):
// [0]            WS_NLL   nll accumulator (zeroed by k_main block 0)
// [8]            WS_DONE  unsigned done-counter for last-block final (zeroed)
// [64, 8256)     MEANS    B*K*C, count-divide fused (k_main cluster blocks)
// [8320, 10368)  APART    1024 * {sum, cnt} (k_main anchor blocks)
#define WS_NLL 0
#define WS_DONE 8
#define WS_MEANS 64
#define WS_APART 8320

__device__ __forceinline__ void pair4(float sx, float sy, float4 xs, float4 ys,
                                      int4 m, float& acc, int& cnt) {
  float dx, dy, d2, v;
  dx = sx - xs.x; dy = sy - ys.x; d2 = dx * dx + dy * dy;
  v = 1.0f - __expf(d2 * -0.1f);
  if (m.x == 1) { acc += v; cnt += 1; }
  dx = sx - xs.y; dy = sy - ys.y; d2 = dx * dx + dy * dy;
  v = 1.0f - __expf(d2 * -0.1f);
  if (m.y == 1) { acc += v; cnt += 1; }
  dx = sx - xs.z; dy = sy - ys.z; d2 = dx * dx + dy * dy;
  v = 1.0f - __expf(d2 * -0.1f);
  if (m.z == 1) { acc += v; cnt += 1; }
  dx = sx - xs.w; dy = sy - ys.w; d2 = dx * dx + dy * dy;
  v = 1.0f - __expf(d2 * -0.1f);
  if (m.w == 1) { acc += v; cnt += 1; }
}

// 1152 blocks x 256, two block-uniform roles (branch at block granularity):
//  blocks [0,128):    cluster means for (b = bid>>5, k = bid&31). Labels to
//                     LDS, ballot-scan (8 ballots/wave), per-row norm inline
//                     (6 shuffles on the already-loaded row), MEANS written
//                     with the count divide fused. Block 0 zeroes NLL/DONE.
//  blocks [128,1152): streaming anchor, 256 blocks per batch. Coordinates
//                     s = emb+absc built in LDS from the raw inputs (16 KB,
//                     L2-shared across blocks) — no prep kernel needed. Then
//                     16 fully-unrolled global-linear int4 mask loads per
//                     thread (column group fixed -> xs/ys read once; row is
//                     block-uniform -> LDS broadcast). Per-block partials.
__global__ __launch_bounds__(256) void k_main(
    const float* __restrict__ emb, const float* __restrict__ absc,
    const float* __restrict__ contr, const int* __restrict__ labels,
    const int* __restrict__ mask, float* __restrict__ ws) {
  __shared__ union {
    struct { float sx[N_]; float sy[N_]; } a;                    // 16 KB
    struct { int lab[N_]; float lsum[4][64]; float lcnt[4]; } c; // 9.3 KB
  } sm;
  __shared__ float red[8];
  int t = threadIdx.x, lane = t & 63, w = t >> 6;
  int bid = blockIdx.x;
  if (bid < 128) {
    int b = bid >> 5, k = bid & 31;
    if (bid == 0 && t == 0) {
      ws[WS_NLL] = 0.0f;
      ((unsigned*)ws)[WS_DONE] = 0u;
    }
    const int4* lab4 = (const int4*)(labels + b * N_);
    int4* l4 = (int4*)sm.c.lab;
    l4[t] = lab4[t];
    l4[t + 256] = lab4[t + 256];
    __syncthreads();
    float acc = 0.0f, cnt = 0.0f;
    for (int g0 = w * 512; g0 < w * 512 + 512; g0 += 64) {
      unsigned long long mb = __ballot(sm.c.lab[g0 + lane] == k);
      while (mb) {
        int bit = __ffsll(mb) - 1;
        mb &= mb - 1;
        int r = g0 + bit;
        float x = contr[(size_t)(b * N_ + r) * C_ + lane];
        float ss = x * x;
#pragma unroll
        for (int off = 32; off > 0; off >>= 1) ss += __shfl_xor(ss, off);
        acc += x * (1.0f / fmaxf(sqrtf(ss), 1e-12f));
        cnt += 1.0f;
      }
    }
    sm.c.lsum[w][lane] = acc;
    if (lane == 0) sm.c.lcnt[w] = cnt;
    __syncthreads();
    if (t < 64) {
      float s = sm.c.lsum[0][t] + sm.c.lsum[1][t] + sm.c.lsum[2][t] + sm.c.lsum[3][t];
      float c = sm.c.lcnt[0] + sm.c.lcnt[1] + sm.c.lcnt[2] + sm.c.lcnt[3];
      ws[WS_MEANS + (b * K_ + k) * C_ + t] = s / fmaxf(c, 1.0f);
    }
  } else {
    int aid = bid - 128;             // [0,1024)
    int b = aid >> 8;                // 256 blocks per batch
    int flat = (aid & 255) * 256 + t;  // [0, 65536) int4 slot within batch
    const float4* e4 = (const float4*)(emb + b * N_ * 2);
    const float4* a4 = (const float4*)(absc + b * N_ * 2);
    for (int i = t; i < N_ / 2; i += 256) {
      float4 ev = e4[i], av = a4[i];
      sm.a.sx[2 * i]     = ev.x + av.x;
      sm.a.sy[2 * i]     = ev.y + av.y;
      sm.a.sx[2 * i + 1] = ev.z + av.z;
      sm.a.sy[2 * i + 1] = ev.w + av.w;
    }
    __syncthreads();
    int cg = flat & 511;             // fixed float4 column group
    float4 xs = ((const float4*)sm.a.sx)[cg];
    float4 ys = ((const float4*)sm.a.sy)[cg];
    const int4* m4 = (const int4*)mask + (size_t)b * (N_ * (size_t)N_ / 4);
    float acc = 0.0f;
    int cnt = 0;
#pragma unroll
    for (int it = 0; it < 16; ++it) {
      int idx = flat + it * 65536;
      int4 m = m4[idx];
      int row = idx >> 9;            // block-uniform -> LDS broadcast
      pair4(sm.a.sx[row], sm.a.sy[row], xs, ys, m, acc, cnt);
    }
    float cntf = (float)cnt;
#pragma unroll
    for (int off = 32; off > 0; off >>= 1) {
      acc += __shfl_xor(acc, off);
      cntf += __shfl_xor(cntf, off);
    }
    if (lane == 0) { red[w * 2] = acc; red[w * 2 + 1] = cntf; }
    __syncthreads();
    if (t == 0) {
      ws[WS_APART + aid * 2 + 0] = red[0] + red[2] + red[4] + red[6];
      ws[WS_APART + aid * 2 + 1] = red[1] + red[3] + red[5] + red[7];
    }
  }
}

// 256 blocks x 128 (2 waves). Block = 32 rows; lane = logit column (wave w
// -> cols [w*64, w*64+64)). Means in 16 float4 VGPRs; rows via LDS
// wave-uniform b128 broadcasts; row norms computed inline. The LAST block to
// finish (device-scope done-counter + fences) reduces the 1024 anchor
// partials and writes the final scalar — no separate k_final dispatch.
__global__ __launch_bounds__(128) void k_logits_final(
    const float* __restrict__ contr, const int* __restrict__ labels,
    float* __restrict__ ws, float* __restrict__ out) {
  __shared__ float lc[32 * C_];    // 8 KB raw rows
  __shared__ float invr[32];
  __shared__ float lm[2][32], lsv[2][32], ltl[32];
  __shared__ float fred[4];
  __shared__ int lastf;
  int t = threadIdx.x, lane = t & 63, w = t >> 6;
  int r0 = blockIdx.x * 32;
  int j = w * 64 + lane;
  const float4* mean4 = (const float4*)(ws + WS_MEANS);
  float4 mk[16];
#pragma unroll
  for (int q = 0; q < 16; ++q) mk[q] = mean4[j * 16 + q];
  const float4* c4 = (const float4*)(contr + (size_t)r0 * C_);
  float4* lc4 = (float4*)lc;
  lc4[t] = c4[t];
  lc4[t + 128] = c4[t + 128];
  lc4[t + 256] = c4[t + 256];
  lc4[t + 384] = c4[t + 384];
  __syncthreads();
  for (int r = w * 16; r < w * 16 + 16; ++r) {
    float x = lc[r * C_ + lane];
    float ss = x * x;
#pragma unroll
    for (int off = 32; off > 0; off >>= 1) ss += __shfl_xor(ss, off);
    if (lane == 0) invr[r] = 1.0f / fmaxf(sqrtf(ss), 1e-12f);
  }
  __syncthreads();
  for (int r = 0; r < 32; ++r) {
    const float4* cr = lc4 + r * 16;
    float acc = 0.0f;
#pragma unroll
    for (int q = 0; q < 16; ++q) {
      float4 cv = cr[q];
      acc += cv.x * mk[q].x + cv.y * mk[q].y + cv.z * mk[q].z + cv.w * mk[q].w;
    }
    acc *= invr[r];
    float m = acc;
#pragma unroll
    for (int off = 32; off > 0; off >>= 1) m = fmaxf(m, __shfl_xor(m, off));
    float s = __expf(acc - m);
#pragma unroll
    for (int off = 32; off > 0; off >>= 1) s += __shfl_xor(s, off);
    int tgt = labels[r0 + r];        // [0,32): wave 0's columns (no batch offset,
    float tl = __shfl(acc, tgt);     //  exactly as the reference computes it)
    if (lane == 0) {
      lm[w][r] = m;
      lsv[w][r] = s;
      if (w == 0) ltl[r] = tl;
    }
  }
  __syncthreads();
  if (t < 32) {
    float m0 = lm[0][t], m1 = lm[1][t];
    float mm = fmaxf(m0, m1);
    float ss = lsv[0][t] * __expf(m0 - mm) + lsv[1][t] * __expf(m1 - mm);
    float nll = (mm + __logf(ss)) - ltl[t];
#pragma unroll
    for (int off = 16; off > 0; off >>= 1) nll += __shfl_xor(nll, off);
    if (t == 0) atomicAdd(&ws[WS_NLL], nll);
  }
  // ---- last-block final combine (release/acquire via done-counter) ----
  __syncthreads();
  if (t == 0) {
    __threadfence();                       // release: my nll add visible
    unsigned v = atomicAdd(&((unsigned*)ws)[WS_DONE], 1u);
    lastf = (v == 255u);
  }
  __syncthreads();
  if (lastf) {
    __threadfence();                       // acquire: all blocks' adds visible
    float a = 0.0f, c = 0.0f;
    for (int i = t; i < 1024; i += 128) {
      a += ws[WS_APART + i * 2 + 0];
      c += ws[WS_APART + i * 2 + 1];
    }
#pragma unroll
    for (int off = 32; off > 0; off >>= 1) {
      a += __shfl_xor(a, off);
      c += __shfl_xor(c, off);
    }
    if (lane == 0) { fred[w * 2] = a; fred[w * 2 + 1] = c; }
    __syncthreads();
    if (t == 0) {
      float at = fred[0] + fred[2];
      float ct = fred[1] + fred[3];
      out[0] = at / ct + 10.0f * ws[WS_NLL] * (1.0f / (float)BN_);
    }
  }
}

extern "C" void kernel_launch(void* const* d_in, const int* in_sizes, int n_in,
                              void* d_out, int out_size, void* d_ws, size_t ws_size,
                              hipStream_t stream) {
  const float* emb    = (const float*)d_in[0];
  const float* contr  = (const float*)d_in[1];
  const float* absc   = (const float*)d_in[2];
  const int*   mask   = (const int*)d_in[3];
  const int*   labels = (const int*)d_in[4];
  float* ws  = (float*)d_ws;
  float* out = (float*)d_out;

  k_main<<<128 + 1024, 256, 0, stream>>>(emb, absc, contr, labels, mask, ws);
  k_logits_final<<<256, 128, 0, stream>>>(contr, labels, ws, out);
}